// Round 17
// baseline (352.707 us; speedup 1.0000x reference)
//
#include <hip/hip_runtime.h>
#include <hip/hip_bf16.h>
#include <stdint.h>

#define DD 32       // input dim
#define HH 64       // hidden dim
#define HSTRIDE 80  // LDS h-row stride in elems (160B)
#define LOG2E 1.44269504088896340736f

typedef float f32x4 __attribute__((ext_vector_type(4)));
typedef short s16x8 __attribute__((ext_vector_type(8)));

// Single-instruction packed f32->bf16 (RNE). Low 16 bits = lo, high = hi.
__device__ __forceinline__ uint32_t cvtpk(float lo, float hi) {
  uint32_t r;
  asm("v_cvt_pk_bf16_f32 %0, %1, %2" : "=v"(r) : "v"(lo), "v"(hi));
  return r;
}

// Relaxed workgroup barrier: order LDS ops only (x-prefetch global loads stay
// in flight). sched_barrier(0) pins the compiler: nothing crosses this point.
#define BAR() do {                                                    \
  asm volatile("s_waitcnt lgkmcnt(0)\n\ts_barrier" ::: "memory");     \
  __builtin_amdgcn_sched_barrier(0);                                  \
} while (0)

// 512 blocks x 4 waves (256 thr). Each block = ONE 4-row chain; wave w owns
// cols 16w..16w+15 for all 4 gates = 4 N-tiles. A-rows dup x4 (arow=lr>>2) =>
// D rows 4lq+r all map to batch lq => lane (lr,lq) owns cell (batch lq, col
// 16w+lr); gates lane-local. 7-trans cell update, 3-way independent MFMA accs.
// PHASE STAGGER: odd blocks sleep ~384cy before the loop so the two co-resident
// blocks per SIMD run anti-phase (one in MFMA/LDS region while the other runs
// its trans chain) — breaks the measured phase-lock (MfmaUtil+VALUBusy ~103%).
__global__ __launch_bounds__(256, 2)
void lstm_fused(const float* __restrict__ x,
                const float* __restrict__ W_ih,
                const float* __restrict__ W_hh,
                const float* __restrict__ b_ih,
                const float* __restrict__ b_hh,
                const float* __restrict__ fc_W,
                const float* __restrict__ fc_b,
                float* __restrict__ out,
                int T)
{
  const int tid   = threadIdx.x;
  const int w     = tid >> 6;      // wave 0..3 -> col group 16w
  const int lane  = tid & 63;
  const int lr    = lane & 15;     // A/D col index within tile
  const int lq    = lane >> 4;     // k-group 0..3; ALSO this lane's batch row
  const int arow  = lr >> 2;       // batch row content of A slot (dup x4)
  const int bm    = blockIdx.x * 4;

  // [buf][row*HSTRIDE]
  __shared__ __align__(16) uint16_t hbuf[2][4 * HSTRIDE];

  // ---- persistent weights: tile j = gate j, cols 16w..16w+15.
  // pre-scaled by log2e (2*log2e for g-gate).
  s16x8 Bx[4], Bh0[4], Bh1[4];
  f32x4 biasv[4];
  #pragma unroll
  for (int j = 0; j < 4; ++j) {
    const int n = 64 * j + 16 * w + lr;
    const float sc = (j == 2) ? (2.0f * LOG2E) : LOG2E;
    {
      const float* p = W_ih + n * DD + lq * 8;
      f32x4 a = *(const f32x4*)p;
      f32x4 b = *(const f32x4*)(p + 4);
      union { uint32_t u[4]; s16x8 s; } pk;
      pk.u[0] = cvtpk(a[0]*sc, a[1]*sc); pk.u[1] = cvtpk(a[2]*sc, a[3]*sc);
      pk.u[2] = cvtpk(b[0]*sc, b[1]*sc); pk.u[3] = cvtpk(b[2]*sc, b[3]*sc);
      Bx[j] = pk.s;
    }
    {
      const float* p = W_hh + n * HH + lq * 8;
      f32x4 a = *(const f32x4*)p;
      f32x4 b = *(const f32x4*)(p + 4);
      union { uint32_t u[4]; s16x8 s; } pk;
      pk.u[0] = cvtpk(a[0]*sc, a[1]*sc); pk.u[1] = cvtpk(a[2]*sc, a[3]*sc);
      pk.u[2] = cvtpk(b[0]*sc, b[1]*sc); pk.u[3] = cvtpk(b[2]*sc, b[3]*sc);
      Bh0[j] = pk.s;
    }
    {
      const float* p = W_hh + n * HH + 32 + lq * 8;
      f32x4 a = *(const f32x4*)p;
      f32x4 b = *(const f32x4*)(p + 4);
      union { uint32_t u[4]; s16x8 s; } pk;
      pk.u[0] = cvtpk(a[0]*sc, a[1]*sc); pk.u[1] = cvtpk(a[2]*sc, a[3]*sc);
      pk.u[2] = cvtpk(b[0]*sc, b[1]*sc); pk.u[3] = cvtpk(b[2]*sc, b[3]*sc);
      Bh1[j] = pk.s;
    }
    const float bb = (b_ih[n] + b_hh[n]) * sc;
    biasv[j] = (f32x4){bb, bb, bb, bb};
  }

  for (int i = tid; i < 2 * 4 * HSTRIDE; i += 256) ((uint16_t*)hbuf)[i] = 0;

  float c = 0.f;  // this lane's single cell: (batch lq, col 16w+lr)

  // hoisted LDS offsets
  const int roff0 = arow * HSTRIDE + 8 * lq;
  const int roff1 = roff0 + 32;
  const int woff  = lq * HSTRIDE + 16 * w + lr;

  const f32x4 zz = {0.f, 0.f, 0.f, 0.f};

  // 2-deep x prefetch, running pointer (addresses dup x4; coalescer dedups)
  const float* xbase = x + (size_t)(bm + arow) * (size_t)T * DD + lq * 8;
  f32x4 xa0 = *(const f32x4*)xbase;        f32x4 xb0 = *(const f32x4*)(xbase + 4);
  f32x4 xa1 = *(const f32x4*)(xbase + DD); f32x4 xb1 = *(const f32x4*)(xbase + DD + 4);
  const float* xp = xbase + 2 * DD;

  __syncthreads();

  // Anti-phase stagger: odd blocks start ~384cy late (half a step). Barriers
  // are per-block, so the offset persists; co-resident blocks stop contending
  // for the same pipe at the same time.
  if (blockIdx.x & 1) __builtin_amdgcn_s_sleep(6);

  auto step = [&](f32x4& xa, f32x4& xb, bool pf,
                  const uint16_t* hr, uint16_t* hw) {
    BAR();  // prev step's h writes visible; global x loads stay in flight

    // h reads (latency covered by the x-pack + x-MFMAs below)
    s16x8 ah0 = *(const s16x8*)(hr + roff0);
    s16x8 ah1 = *(const s16x8*)(hr + roff1);

    // pack x into A fragment, then issue t+2 prefetch
    union { uint32_t u[4]; s16x8 s; } ax;
    ax.u[0] = cvtpk(xa[0], xa[1]); ax.u[1] = cvtpk(xa[2], xa[3]);
    ax.u[2] = cvtpk(xb[0], xb[1]); ax.u[3] = cvtpk(xb[2], xb[3]);
    if (pf) {
      xa = *(const f32x4*)xp; xb = *(const f32x4*)(xp + 4); xp += DD;
    }

    // MFMA cluster (prioritized): 3 fully independent accumulators — no
    // MFMA->MFMA chaining anywhere.
    __builtin_amdgcn_s_setprio(1);
    f32x4 accx[4], acch0[4], acch1[4];
    #pragma unroll
    for (int j = 0; j < 4; ++j)
      accx[j]  = __builtin_amdgcn_mfma_f32_16x16x32_bf16(ax.s, Bx[j], biasv[j], 0, 0, 0);
    #pragma unroll
    for (int j = 0; j < 4; ++j)
      acch0[j] = __builtin_amdgcn_mfma_f32_16x16x32_bf16(ah0, Bh0[j], zz, 0, 0, 0);
    #pragma unroll
    for (int j = 0; j < 4; ++j)
      acch1[j] = __builtin_amdgcn_mfma_f32_16x16x32_bf16(ah1, Bh1[j], zz, 0, 0, 0);
    __builtin_amdgcn_s_setprio(0);

    // gates = x-part + both h-parts; lane-local (batch = lq)
    float g0 = (accx[0][0] + acch0[0][0]) + acch1[0][0];
    float g1 = (accx[1][0] + acch0[1][0]) + acch1[1][0];
    float g2 = (accx[2][0] + acch0[2][0]) + acch1[2][0];
    float g3 = (accx[3][0] + acch0[3][0]) + acch1[3][0];

    // 7-trans cell update (common-denominator forms):
    //  c' = [c(1+A)(1+Q) + (Q-1)(1+F)] / [(1+A)(1+Q)(1+F)]
    //  h  = (S-1) / [(1+O)(1+S)], S = exp2(2log2e * c')
    float A = __builtin_amdgcn_exp2f(-g0);
    float F = __builtin_amdgcn_exp2f(-g1);
    float Q = __builtin_amdgcn_exp2f(g2);
    float O = __builtin_amdgcn_exp2f(-g3);
    float u  = 1.f + A;
    float v  = 1.f + Q;
    float wf = 1.f + F;
    float M  = u * v;
    float D  = M * wf;
    float num = fmaf(c, M, (Q - 1.f) * wf);
    float r  = __builtin_amdgcn_rcpf(D);
    c = num * r;
    float sarg = __builtin_amdgcn_fmed3f((2.0f * LOG2E) * c, -80.f, 80.f);
    float S  = __builtin_amdgcn_exp2f(sarg);
    float r2 = __builtin_amdgcn_rcpf((1.f + O) * (1.f + S));
    float hv = (S - 1.f) * r2;
    hw[woff] = (uint16_t)cvtpk(hv, hv);  // one b16 write per lane
  };

  for (int t = 0; t < T - 2; t += 2) {
    step(xa0, xb0, true, hbuf[0], hbuf[1]);
    step(xa1, xb1, true, hbuf[1], hbuf[0]);
  }
  step(xa0, xb0, false, hbuf[0], hbuf[1]);
  step(xa1, xb1, false, hbuf[1], hbuf[0]);

  __syncthreads();  // final h (bf16) in hbuf[0], linear [row][col]

  // ---- epilogue: logits = h_last @ fc_W^T + fc_b (4 rows x 10 cols) ----
  if (tid < 40) {
    const int m = tid / 10, cl = tid % 10;
    float s = fc_b[cl];
    const float* wr = fc_W + cl * HH;
    const uint16_t* hm = hbuf[0] + m * HSTRIDE;
    #pragma unroll
    for (int k = 0; k < HH; ++k) {
      union { uint32_t u; float f; } v;
      v.u = (uint32_t)hm[k] << 16;
      s += v.f * wr[k];
    }
    out[(size_t)(bm + m) * 10 + cl] = s;
  }
}

extern "C" void kernel_launch(void* const* d_in, const int* in_sizes, int n_in,
                              void* d_out, int out_size, void* d_ws, size_t ws_size,
                              hipStream_t stream) {
  const float* x    = (const float*)d_in[0];
  const float* W_ih = (const float*)d_in[1];
  const float* W_hh = (const float*)d_in[2];
  const float* b_ih = (const float*)d_in[3];
  const float* b_hh = (const float*)d_in[4];
  const float* fc_W = (const float*)d_in[5];
  const float* fc_b = (const float*)d_in[6];
  float* out = (float*)d_out;

  const int B = out_size / 10;            // 2048
  const int T = in_sizes[0] / (B * DD);   // 1024

  dim3 grid(B / 4), block(256);
  hipLaunchKernelGGL(lstm_fused, grid, block, 0, stream,
                     x, W_ih, W_hh, b_ih, b_hh, fc_W, fc_b, out, T);
}

// Round 18
// 334.128 us; speedup vs baseline: 1.0556x; 1.0556x over previous
//
#include <hip/hip_runtime.h>
#include <hip/hip_bf16.h>
#include <stdint.h>

#define DD 32       // input dim
#define HH 64       // hidden dim
#define HSTRIDE 80  // LDS h-row stride in elems (160B)
#define LOG2E 1.44269504088896340736f

typedef float f32x4 __attribute__((ext_vector_type(4)));
typedef short s16x8 __attribute__((ext_vector_type(8)));

// Single-instruction packed f32->bf16 (RNE). Low 16 bits = lo, high = hi.
__device__ __forceinline__ uint32_t cvtpk(float lo, float hi) {
  uint32_t r;
  asm("v_cvt_pk_bf16_f32 %0, %1, %2" : "=v"(r) : "v"(lo), "v"(hi));
  return r;
}

// Relaxed workgroup barrier: order LDS ops only (x-prefetch global loads stay
// in flight). sched_barrier(0) pins the compiler: nothing crosses this point.
#define BAR() do {                                                    \
  asm volatile("s_waitcnt lgkmcnt(0)\n\ts_barrier" ::: "memory");     \
  __builtin_amdgcn_sched_barrier(0);                                  \
} while (0)

// 512 blocks x 4 waves (256 thr). Each block = ONE 4-row chain; wave w owns
// cols 16w..16w+15 for all 4 gates = 4 N-tiles. A-rows dup x4 (arow=lr>>2) =>
// D rows 4lq+r all map to batch lq => lane (lr,lq) owns cell (batch lq, col
// 16w+lr); gates lane-local. 7-trans cell update. R16 schedule (proven 340us):
// BAR -> ds_read -> x-pack/prefetch/x-MFMA (covers LDS latency) -> h-MFMA
// 2-deep -> gates -> cell -> h-write; setprio(1) around the MFMA cluster.
// PHASE STAGGER v2 (pairing-agnostic): co-resident pairs are (b,b+256) or
// (2i,2i+1); sleep 6 units (~384cy ~ half step) per differing bit so either
// pairing lands anti-phase. Anti-phase is contention-stable across barriers.
__global__ __launch_bounds__(256, 2)
void lstm_fused(const float* __restrict__ x,
                const float* __restrict__ W_ih,
                const float* __restrict__ W_hh,
                const float* __restrict__ b_ih,
                const float* __restrict__ b_hh,
                const float* __restrict__ fc_W,
                const float* __restrict__ fc_b,
                float* __restrict__ out,
                int T)
{
  const int tid   = threadIdx.x;
  const int w     = tid >> 6;      // wave 0..3 -> col group 16w
  const int lane  = tid & 63;
  const int lr    = lane & 15;     // A/D col index within tile
  const int lq    = lane >> 4;     // k-group 0..3; ALSO this lane's batch row
  const int arow  = lr >> 2;       // batch row content of A slot (dup x4)
  const int bm    = blockIdx.x * 4;

  // [buf][row*HSTRIDE]
  __shared__ __align__(16) uint16_t hbuf[2][4 * HSTRIDE];

  // ---- persistent weights: tile j = gate j, cols 16w..16w+15.
  // pre-scaled by log2e (2*log2e for g-gate).
  s16x8 Bx[4], Bh0[4], Bh1[4];
  f32x4 biasv[4];
  #pragma unroll
  for (int j = 0; j < 4; ++j) {
    const int n = 64 * j + 16 * w + lr;
    const float sc = (j == 2) ? (2.0f * LOG2E) : LOG2E;
    {
      const float* p = W_ih + n * DD + lq * 8;
      f32x4 a = *(const f32x4*)p;
      f32x4 b = *(const f32x4*)(p + 4);
      union { uint32_t u[4]; s16x8 s; } pk;
      pk.u[0] = cvtpk(a[0]*sc, a[1]*sc); pk.u[1] = cvtpk(a[2]*sc, a[3]*sc);
      pk.u[2] = cvtpk(b[0]*sc, b[1]*sc); pk.u[3] = cvtpk(b[2]*sc, b[3]*sc);
      Bx[j] = pk.s;
    }
    {
      const float* p = W_hh + n * HH + lq * 8;
      f32x4 a = *(const f32x4*)p;
      f32x4 b = *(const f32x4*)(p + 4);
      union { uint32_t u[4]; s16x8 s; } pk;
      pk.u[0] = cvtpk(a[0]*sc, a[1]*sc); pk.u[1] = cvtpk(a[2]*sc, a[3]*sc);
      pk.u[2] = cvtpk(b[0]*sc, b[1]*sc); pk.u[3] = cvtpk(b[2]*sc, b[3]*sc);
      Bh0[j] = pk.s;
    }
    {
      const float* p = W_hh + n * HH + 32 + lq * 8;
      f32x4 a = *(const f32x4*)p;
      f32x4 b = *(const f32x4*)(p + 4);
      union { uint32_t u[4]; s16x8 s; } pk;
      pk.u[0] = cvtpk(a[0]*sc, a[1]*sc); pk.u[1] = cvtpk(a[2]*sc, a[3]*sc);
      pk.u[2] = cvtpk(b[0]*sc, b[1]*sc); pk.u[3] = cvtpk(b[2]*sc, b[3]*sc);
      Bh1[j] = pk.s;
    }
    const float bb = (b_ih[n] + b_hh[n]) * sc;
    biasv[j] = (f32x4){bb, bb, bb, bb};
  }

  for (int i = tid; i < 2 * 4 * HSTRIDE; i += 256) ((uint16_t*)hbuf)[i] = 0;

  float c = 0.f;  // this lane's single cell: (batch lq, col 16w+lr)

  // hoisted LDS offsets
  const int roff0 = arow * HSTRIDE + 8 * lq;
  const int roff1 = roff0 + 32;
  const int woff  = lq * HSTRIDE + 16 * w + lr;

  const f32x4 zz = {0.f, 0.f, 0.f, 0.f};

  // 2-deep x prefetch, running pointer (addresses dup x4; coalescer dedups)
  const float* xbase = x + (size_t)(bm + arow) * (size_t)T * DD + lq * 8;
  f32x4 xa0 = *(const f32x4*)xbase;        f32x4 xb0 = *(const f32x4*)(xbase + 4);
  f32x4 xa1 = *(const f32x4*)(xbase + DD); f32x4 xb1 = *(const f32x4*)(xbase + DD + 4);
  const float* xp = xbase + 2 * DD;

  __syncthreads();

  // Anti-phase stagger, pairing-agnostic: ~384cy per differing bit (bit0 for
  // (2i,2i+1) pairing, bit8 for (b,b+256) pairing). Offset persists: barriers
  // are per-block, and anti-phase is contention-stable.
  if (blockIdx.x & 1)   __builtin_amdgcn_s_sleep(6);
  if (blockIdx.x & 256) __builtin_amdgcn_s_sleep(6);

  auto step = [&](f32x4& xa, f32x4& xb, bool pf,
                  const uint16_t* hr, uint16_t* hw) {
    BAR();  // prev step's h writes visible; global x loads stay in flight

    // h reads (latency covered by the x-pack + x-MFMAs below)
    s16x8 ah0 = *(const s16x8*)(hr + roff0);
    s16x8 ah1 = *(const s16x8*)(hr + roff1);

    // pack x into A fragment, then issue t+2 prefetch
    union { uint32_t u[4]; s16x8 s; } ax;
    ax.u[0] = cvtpk(xa[0], xa[1]); ax.u[1] = cvtpk(xa[2], xa[3]);
    ax.u[2] = cvtpk(xb[0], xb[1]); ax.u[3] = cvtpk(xb[2], xb[3]);
    if (pf) {
      xa = *(const f32x4*)xp; xb = *(const f32x4*)(xp + 4); xp += DD;
    }

    // MFMA cluster (prioritized): x-part into accx (independent of LDS),
    // h-part into acch (2-deep chain). Gates add the two at the end.
    __builtin_amdgcn_s_setprio(1);
    f32x4 accx[4], acch[4];
    #pragma unroll
    for (int j = 0; j < 4; ++j)
      accx[j] = __builtin_amdgcn_mfma_f32_16x16x32_bf16(ax.s, Bx[j], biasv[j], 0, 0, 0);
    #pragma unroll
    for (int j = 0; j < 4; ++j)
      acch[j] = __builtin_amdgcn_mfma_f32_16x16x32_bf16(ah0, Bh0[j], zz, 0, 0, 0);
    #pragma unroll
    for (int j = 0; j < 4; ++j)
      acch[j] = __builtin_amdgcn_mfma_f32_16x16x32_bf16(ah1, Bh1[j], acch[j], 0, 0, 0);
    __builtin_amdgcn_s_setprio(0);

    // gates = x-part + h-part; lane-local (batch = lq)
    float g0 = accx[0][0] + acch[0][0];
    float g1 = accx[1][0] + acch[1][0];
    float g2 = accx[2][0] + acch[2][0];
    float g3 = accx[3][0] + acch[3][0];

    // 7-trans cell update (common-denominator forms):
    //  c' = [c(1+A)(1+Q) + (Q-1)(1+F)] / [(1+A)(1+Q)(1+F)]
    //  h  = (S-1) / [(1+O)(1+S)], S = exp2(2log2e * c')
    float A = __builtin_amdgcn_exp2f(-g0);
    float F = __builtin_amdgcn_exp2f(-g1);
    float Q = __builtin_amdgcn_exp2f(g2);
    float O = __builtin_amdgcn_exp2f(-g3);
    float u  = 1.f + A;
    float v  = 1.f + Q;
    float wf = 1.f + F;
    float M  = u * v;
    float D  = M * wf;
    float num = fmaf(c, M, (Q - 1.f) * wf);
    float r  = __builtin_amdgcn_rcpf(D);
    c = num * r;
    float sarg = __builtin_amdgcn_fmed3f((2.0f * LOG2E) * c, -80.f, 80.f);
    float S  = __builtin_amdgcn_exp2f(sarg);
    float r2 = __builtin_amdgcn_rcpf((1.f + O) * (1.f + S));
    float hv = (S - 1.f) * r2;
    hw[woff] = (uint16_t)cvtpk(hv, hv);  // one b16 write per lane
  };

  for (int t = 0; t < T - 2; t += 2) {
    step(xa0, xb0, true, hbuf[0], hbuf[1]);
    step(xa1, xb1, true, hbuf[1], hbuf[0]);
  }
  step(xa0, xb0, false, hbuf[0], hbuf[1]);
  step(xa1, xb1, false, hbuf[1], hbuf[0]);

  __syncthreads();  // final h (bf16) in hbuf[0], linear [row][col]

  // ---- epilogue: logits = h_last @ fc_W^T + fc_b (4 rows x 10 cols) ----
  if (tid < 40) {
    const int m = tid / 10, cl = tid % 10;
    float s = fc_b[cl];
    const float* wr = fc_W + cl * HH;
    const uint16_t* hm = hbuf[0] + m * HSTRIDE;
    #pragma unroll
    for (int k = 0; k < HH; ++k) {
      union { uint32_t u; float f; } v;
      v.u = (uint32_t)hm[k] << 16;
      s += v.f * wr[k];
    }
    out[(size_t)(bm + m) * 10 + cl] = s;
  }
}

extern "C" void kernel_launch(void* const* d_in, const int* in_sizes, int n_in,
                              void* d_out, int out_size, void* d_ws, size_t ws_size,
                              hipStream_t stream) {
  const float* x    = (const float*)d_in[0];
  const float* W_ih = (const float*)d_in[1];
  const float* W_hh = (const float*)d_in[2];
  const float* b_ih = (const float*)d_in[3];
  const float* b_hh = (const float*)d_in[4];
  const float* fc_W = (const float*)d_in[5];
  const float* fc_b = (const float*)d_in[6];
  float* out = (float*)d_out;

  const int B = out_size / 10;            // 2048
  const int T = in_sizes[0] / (B * DD);   // 1024

  dim3 grid(B / 4), block(256);
  hipLaunchKernelGGL(lstm_fused, grid, block, 0, stream,
                     x, W_ih, W_hh, b_ih, b_hh, fc_W, fc_b, out, T);
}